// Round 1
// baseline (743.753 us; speedup 1.0000x reference)
//
#include <hip/hip_runtime.h>
#include <cstdint>

#define C_DIM 1024
#define N_DIM 36864   // 192*192
#define SPLITK 4
#define KCHUNK (N_DIM / SPLITK)   // 9216

typedef unsigned short ushort_t;
typedef __attribute__((ext_vector_type(8))) short bf16x8;   // 8 bf16 in 4 VGPRs
typedef __attribute__((ext_vector_type(4))) float f32x4;

__device__ __forceinline__ ushort_t f2b(float f) {
    unsigned u = __float_as_uint(f);
    u = (u + 0x7fffu + ((u >> 16) & 1u)) >> 16;   // RN-even
    return (ushort_t)u;
}
__device__ __forceinline__ float b2f(ushort_t b) {
    return __uint_as_float(((unsigned)b) << 16);
}

// async global->LDS, 16B per lane; lds base must be wave-uniform, HW adds lane*16
__device__ __forceinline__ void async16(const void* g, const void* lds) {
    __builtin_amdgcn_global_load_lds(
        (const __attribute__((address_space(1))) unsigned int*)(uintptr_t)g,
        (__attribute__((address_space(3))) unsigned int*)(uint32_t)(uintptr_t)lds,
        16, 0, 0);
}

// ---------------- K1: x (fp32) -> Ph, Pl (bf16 split) ----------------
__global__ __launch_bounds__(256) void k_convert(const float* __restrict__ x,
                                                 ushort_t* __restrict__ ph,
                                                 ushort_t* __restrict__ pl) {
    int i = blockIdx.x * 256 + threadIdx.x;        // float4 index
    float4 v = ((const float4*)x)[i];
    ushort4 h, l;
    h.x = f2b(v.x); l.x = f2b(v.x - b2f(h.x));
    h.y = f2b(v.y); l.y = f2b(v.y - b2f(h.y));
    h.z = f2b(v.z); l.z = f2b(v.z - b2f(h.z));
    h.w = f2b(v.w); l.w = f2b(v.w - b2f(h.w));
    ((ushort4*)ph)[i] = h;
    ((ushort4*)pl)[i] = l;
}

// ---------------- K2: E-GEMM partials. G1 = Ph*Ph^T, G2 = Ph*Pl^T ----------------
// block = 64x64 tile, 4 waves of 32x32, BK=32, split-K over gridDim.z
__global__ __launch_bounds__(256) void k_egemm(const ushort_t* __restrict__ ph,
                                               const ushort_t* __restrict__ pl,
                                               float* __restrict__ g1,
                                               float* __restrict__ g2) {
    __shared__ __align__(16) ushort_t sA [64 * 32];
    __shared__ __align__(16) ushort_t sBh[64 * 32];
    __shared__ __align__(16) ushort_t sBl[64 * 32];

    const int t = threadIdx.x;
    const int w = t >> 6;
    const int L = t & 63;
    const int c0 = blockIdx.x << 6;
    const int d0 = blockIdx.y << 6;
    const int kb = blockIdx.z * KCHUNK;

    // staging: wave w stages rows [16w,16w+16) of each tile; lane: row=L>>2, 8-elem col chunk=(L&3)*8
    const int srow = (w << 4) + (L >> 2);
    const int scol = (L & 3) << 3;
    const ushort_t* gA  = ph + (size_t)(c0 + srow) * N_DIM + kb + scol;
    const ushort_t* gBh = ph + (size_t)(d0 + srow) * N_DIM + kb + scol;
    const ushort_t* gBl = pl + (size_t)(d0 + srow) * N_DIM + kb + scol;
    const ushort_t* lA  = sA  + ((w << 4) << 5);
    const ushort_t* lBh = sBh + ((w << 4) << 5);
    const ushort_t* lBl = sBl + ((w << 4) << 5);

    const int wm = (w >> 1) << 5;   // wave row offset in tile
    const int wn = (w & 1) << 5;    // wave col offset
    const int lm = L & 15, q = L >> 4;

    f32x4 acc1[2][2], acc2[2][2];
#pragma unroll
    for (int a = 0; a < 2; ++a)
#pragma unroll
        for (int b = 0; b < 2; ++b) { acc1[a][b] = (f32x4)0.0f; acc2[a][b] = (f32x4)0.0f; }

    for (int kk = 0; kk < KCHUNK; kk += 32) {
        async16(gA, lA);
        async16(gBh, lBh);
        async16(gBl, lBl);
        gA += 32; gBh += 32; gBl += 32;
        __syncthreads();

        bf16x8 a[2], bh[2], bl[2];
#pragma unroll
        for (int mt = 0; mt < 2; ++mt)
            a[mt] = *(const bf16x8*)(sA + ((wm + (mt << 4) + lm) << 5) + (q << 3));
#pragma unroll
        for (int nt = 0; nt < 2; ++nt) {
            bh[nt] = *(const bf16x8*)(sBh + ((wn + (nt << 4) + lm) << 5) + (q << 3));
            bl[nt] = *(const bf16x8*)(sBl + ((wn + (nt << 4) + lm) << 5) + (q << 3));
        }
#pragma unroll
        for (int mt = 0; mt < 2; ++mt)
#pragma unroll
            for (int nt = 0; nt < 2; ++nt) {
                acc1[mt][nt] = __builtin_amdgcn_mfma_f32_16x16x32_bf16(a[mt], bh[nt], acc1[mt][nt], 0, 0, 0);
                acc2[mt][nt] = __builtin_amdgcn_mfma_f32_16x16x32_bf16(a[mt], bl[nt], acc2[mt][nt], 0, 0, 0);
            }
        __syncthreads();
    }

    const size_t zb = (size_t)blockIdx.z << 20;
#pragma unroll
    for (int mt = 0; mt < 2; ++mt)
#pragma unroll
        for (int nt = 0; nt < 2; ++nt)
#pragma unroll
            for (int r = 0; r < 4; ++r) {
                int cg = c0 + wm + (mt << 4) + (q << 2) + r;   // D row = (L>>4)*4 + reg
                int dg = d0 + wn + (nt << 4) + lm;             // D col = L&15
                size_t o = zb + ((size_t)cg << 10) + dg;
                g1[o] = acc1[mt][nt][r];
                g2[o] = acc2[mt][nt][r];
            }
}

// ---------------- K3: row softmax of (rowmin trick): A = softmax(-E) ----------------
__global__ __launch_bounds__(256) void k_softmax(const float* __restrict__ g1,
                                                 const float* __restrict__ g2,
                                                 ushort_t* __restrict__ att) {
    const int c = blockIdx.x;
    const int t = threadIdx.x;
    __shared__ float red[4];
    __shared__ float bcast;

    float e[4];
#pragma unroll
    for (int i = 0; i < 4; ++i) {
        int d = t + (i << 8);
        float s = 0.0f;
#pragma unroll
        for (int z = 0; z < SPLITK; ++z) {
            size_t b1 = ((size_t)z << 20) + ((size_t)c << 10) + d;
            size_t b2 = ((size_t)z << 20) + ((size_t)d << 10) + c;
            s += g1[b1] + g2[b1] + g2[b2];   // E = G1 + G2 + G2^T
        }
        e[i] = s;
    }
    // row min (softmax(-E): shift by row min of E)
    float m = fminf(fminf(e[0], e[1]), fminf(e[2], e[3]));
#pragma unroll
    for (int off = 32; off > 0; off >>= 1) m = fminf(m, __shfl_down(m, off));
    if ((t & 63) == 0) red[t >> 6] = m;
    __syncthreads();
    if (t == 0) bcast = fminf(fminf(red[0], red[1]), fminf(red[2], red[3]));
    __syncthreads();
    m = bcast;

    float wv[4];
    float s = 0.0f;
#pragma unroll
    for (int i = 0; i < 4; ++i) { wv[i] = expf(m - e[i]); s += wv[i]; }
#pragma unroll
    for (int off = 32; off > 0; off >>= 1) s += __shfl_down(s, off);
    if ((t & 63) == 0) red[t >> 6] = s;
    __syncthreads();
    if (t == 0) bcast = red[0] + red[1] + red[2] + red[3];
    __syncthreads();
    float inv = 1.0f / bcast;
#pragma unroll
    for (int i = 0; i < 4; ++i)
        att[((size_t)c << 10) + t + (i << 8)] = f2b(wv[i] * inv);
}

// ---------------- K3b: transpose Ph [1024][36864] -> PhT [36864][1024] ----------------
__global__ __launch_bounds__(256) void k_transpose(const ushort_t* __restrict__ ph,
                                                   ushort_t* __restrict__ pht) {
    __shared__ __align__(16) ushort_t tile[64][72];   // pad 8 to keep 16B alignment
    const int t = threadIdx.x;
    const int i = t >> 2, qd = t & 3;
    const int c0 = blockIdx.y << 6;
    const size_t n0 = (size_t)blockIdx.x << 6;

    const ushort_t* src = ph + (size_t)(c0 + i) * N_DIM + n0 + (qd << 4);
    uint4 v0 = *(const uint4*)src;
    uint4 v1 = *(const uint4*)(src + 8);
    *(uint4*)&tile[i][qd << 4]       = v0;
    *(uint4*)&tile[i][(qd << 4) + 8] = v1;
    __syncthreads();

    ushort_t tmp[16];
#pragma unroll
    for (int u = 0; u < 16; ++u) tmp[u] = tile[(qd << 4) + u][i];
    ushort_t* dst = pht + (n0 + i) * C_DIM + c0 + (qd << 4);
    *(uint4*)dst       = *(uint4*)tmp;
    *(uint4*)(dst + 8) = *(uint4*)(tmp + 8);
}

// ---------------- K4: O = A * P, out = gamma*O + x. 128x128 tile, 4 waves of 64x64 ----------------
__global__ __launch_bounds__(256) void k_ogemm(const ushort_t* __restrict__ att,
                                               const ushort_t* __restrict__ pht,
                                               const float* __restrict__ x,
                                               const float* __restrict__ gamma,
                                               float* __restrict__ out) {
    __shared__ __align__(16) ushort_t sA[128 * 32];
    __shared__ __align__(16) ushort_t sB[128 * 32];

    const int t = threadIdx.x;
    const int w = t >> 6, L = t & 63;
    const int n0 = blockIdx.x << 7;
    const int c0 = blockIdx.y << 7;
    const int srow = L >> 2, scol = (L & 3) << 3;

    const int wm = (w >> 1) << 6, wn = (w & 1) << 6;
    const int lm = L & 15, q = L >> 4;

    f32x4 acc[4][4];
#pragma unroll
    for (int a = 0; a < 4; ++a)
#pragma unroll
        for (int b = 0; b < 4; ++b) acc[a][b] = (f32x4)0.0f;

    for (int k = 0; k < C_DIM; k += 32) {
#pragma unroll
        for (int j = 0; j < 4; ++j) {
            int ch = (w << 2) + j;                    // 0..7 -> sA rows, 8..15 -> sB rows
            int row = ((ch & 7) << 4) + srow;
            const ushort_t* src = (ch < 8)
                ? att + (size_t)(c0 + row) * C_DIM + k + scol
                : pht + (size_t)(n0 + row) * C_DIM + k + scol;
            ushort_t* base = (ch < 8) ? sA : sB;
            async16(src, base + (((ch & 7) << 4) << 5));
        }
        __syncthreads();

        bf16x8 a[4], b[4];
#pragma unroll
        for (int mt = 0; mt < 4; ++mt)
            a[mt] = *(const bf16x8*)(sA + ((wm + (mt << 4) + lm) << 5) + (q << 3));
#pragma unroll
        for (int nt = 0; nt < 4; ++nt)
            b[nt] = *(const bf16x8*)(sB + ((wn + (nt << 4) + lm) << 5) + (q << 3));
#pragma unroll
        for (int mt = 0; mt < 4; ++mt)
#pragma unroll
            for (int nt = 0; nt < 4; ++nt)
                acc[mt][nt] = __builtin_amdgcn_mfma_f32_16x16x32_bf16(a[mt], b[nt], acc[mt][nt], 0, 0, 0);
        __syncthreads();
    }

    const float g = gamma[0];
#pragma unroll
    for (int mt = 0; mt < 4; ++mt)
#pragma unroll
        for (int nt = 0; nt < 4; ++nt)
#pragma unroll
            for (int r = 0; r < 4; ++r) {
                int cg = c0 + wm + (mt << 4) + (q << 2) + r;
                int ng = n0 + wn + (nt << 4) + lm;
                size_t o = (size_t)cg * N_DIM + ng;
                out[o] = g * acc[mt][nt][r] + x[o];
            }
}

extern "C" void kernel_launch(void* const* d_in, const int* in_sizes, int n_in,
                              void* d_out, int out_size, void* d_ws, size_t ws_size,
                              hipStream_t stream) {
    const float* x     = (const float*)d_in[0];
    const float* gamma = (const float*)d_in[1];
    float* out = (float*)d_out;
    char* ws = (char*)d_ws;

    // workspace layout (total ~178 MiB)
    ushort_t* ph  = (ushort_t*)(ws);                       // 75,497,472 B
    ushort_t* pl  = (ushort_t*)(ws + 75497472ull);         // 75,497,472 B (reused as PhT)
    float*    g1  = (float*)   (ws + 150994944ull);        // 16,777,216 B
    float*    g2  = (float*)   (ws + 167772160ull);        // 16,777,216 B
    ushort_t* att = (ushort_t*)(ws + 184549376ull);        //  2,097,152 B
    ushort_t* pht = pl;   // transpose written after E-GEMM has consumed Pl

    k_convert<<<dim3((C_DIM * (size_t)N_DIM / 4) / 256), 256, 0, stream>>>(x, ph, pl);

    k_egemm<<<dim3(16, 16, SPLITK), 256, 0, stream>>>(ph, pl, g1, g2);

    k_softmax<<<dim3(C_DIM), 256, 0, stream>>>(g1, g2, att);

    k_transpose<<<dim3(N_DIM / 64, C_DIM / 64), 256, 0, stream>>>(ph, pht);

    k_ogemm<<<dim3(N_DIM / 128, C_DIM / 128), 256, 0, stream>>>(att, pht, x, gamma, out);
}

// Round 2
// 697.334 us; speedup vs baseline: 1.0666x; 1.0666x over previous
//
#include <hip/hip_runtime.h>
#include <cstdint>

#define C_DIM 1024
#define N_DIM 36864   // 192*192

typedef unsigned short ushort_t;
typedef __attribute__((ext_vector_type(8))) short bf16x8;   // 8 bf16 in 4 VGPRs
typedef __attribute__((ext_vector_type(4))) float f32x4;

__device__ __forceinline__ ushort_t f2b(float f) {
    unsigned u = __float_as_uint(f);
    u = (u + 0x7fffu + ((u >> 16) & 1u)) >> 16;   // RN-even
    return (ushort_t)u;
}
__device__ __forceinline__ float b2f(ushort_t b) {
    return __uint_as_float(((unsigned)b) << 16);
}

// async global->LDS, 16B per lane; lds base must be wave-uniform, HW adds lane*16
__device__ __forceinline__ void async16(const void* g, const void* lds) {
    __builtin_amdgcn_global_load_lds(
        (const __attribute__((address_space(1))) unsigned int*)(uintptr_t)g,
        (__attribute__((address_space(3))) unsigned int*)(uint32_t)(uintptr_t)lds,
        16, 0, 0);
}

// ---------------- K1: x (fp32) -> Ph, Pl (bf16 split) ----------------
__global__ __launch_bounds__(256) void k_convert(const float* __restrict__ x,
                                                 ushort_t* __restrict__ ph,
                                                 ushort_t* __restrict__ pl) {
    int i = blockIdx.x * 256 + threadIdx.x;        // float4 index
    float4 v = ((const float4*)x)[i];
    ushort4 h, l;
    h.x = f2b(v.x); l.x = f2b(v.x - b2f(h.x));
    h.y = f2b(v.y); l.y = f2b(v.y - b2f(h.y));
    h.z = f2b(v.z); l.z = f2b(v.z - b2f(h.z));
    h.w = f2b(v.w); l.w = f2b(v.w - b2f(h.w));
    ((ushort4*)ph)[i] = h;
    ((ushort4*)pl)[i] = l;
}

// ---------------- K2: E-GEMM partials. G1 = Ph*Ph^T, G2 = Ph*Pl^T ----------------
// tile 128(c) x 64(d), BK=32, 4 waves of 64x32, dual MFMA chain, split-K over gridDim.z
__global__ __launch_bounds__(256) void k_egemm(const ushort_t* __restrict__ ph,
                                               const ushort_t* __restrict__ pl,
                                               float* __restrict__ g1,
                                               float* __restrict__ g2,
                                               int kchunk) {
    __shared__ __align__(16) ushort_t sA [128 * 32];   // 8 KB
    __shared__ __align__(16) ushort_t sBh[64 * 32];    // 4 KB
    __shared__ __align__(16) ushort_t sBl[64 * 32];    // 4 KB

    const int t = threadIdx.x;
    const int w = t >> 6;
    const int L = t & 63;
    const int c0 = blockIdx.x << 7;
    const int d0 = blockIdx.y << 6;
    const int kb = blockIdx.z * kchunk;

    // staging: each async16 covers 16 rows (32 bf16 = 64B per row); lane: row=L>>2, col=(L&3)*8
    const int lrow = L >> 2, lcol = (L & 3) << 3;

    // wave w stages sA rows [32w,32w+32); waves 0,1 stage sBh rows [32(w&1),+32); waves 2,3 sBl
    const ushort_t* gA0 = ph + (size_t)(c0 + (w << 5) + lrow) * N_DIM + kb + lcol;
    const ushort_t* gB0 = (w < 2 ? ph : pl) +
                          (size_t)(d0 + ((w & 1) << 5) + lrow) * N_DIM + kb + lcol;
    ushort_t* lA0 = sA + ((w << 5) << 5);
    ushort_t* lB0 = (w < 2 ? sBh : sBl) + (((w & 1) << 5) << 5);

    const int wm = (w >> 1) << 6;   // wave row offset (c) 0/64
    const int wn = (w & 1) << 5;    // wave col offset (d) 0/32
    const int lm = L & 15, q = L >> 4;

    f32x4 acc1[4][2], acc2[4][2];
#pragma unroll
    for (int a = 0; a < 4; ++a)
#pragma unroll
        for (int b = 0; b < 2; ++b) { acc1[a][b] = (f32x4)0.0f; acc2[a][b] = (f32x4)0.0f; }

    for (int kk = 0; kk < kchunk; kk += 32) {
        async16(gA0,                 lA0);
        async16(gA0 + 16 * N_DIM,    lA0 + 16 * 32);
        async16(gB0,                 lB0);
        async16(gB0 + 16 * N_DIM,    lB0 + 16 * 32);
        gA0 += 32; gB0 += 32;
        __syncthreads();

        bf16x8 a[4], bh[2], bl[2];
#pragma unroll
        for (int mt = 0; mt < 4; ++mt)
            a[mt] = *(const bf16x8*)(sA + ((wm + (mt << 4) + lm) << 5) + (q << 3));
#pragma unroll
        for (int nt = 0; nt < 2; ++nt) {
            bh[nt] = *(const bf16x8*)(sBh + ((wn + (nt << 4) + lm) << 5) + (q << 3));
            bl[nt] = *(const bf16x8*)(sBl + ((wn + (nt << 4) + lm) << 5) + (q << 3));
        }
#pragma unroll
        for (int mt = 0; mt < 4; ++mt)
#pragma unroll
            for (int nt = 0; nt < 2; ++nt) {
                acc1[mt][nt] = __builtin_amdgcn_mfma_f32_16x16x32_bf16(a[mt], bh[nt], acc1[mt][nt], 0, 0, 0);
                acc2[mt][nt] = __builtin_amdgcn_mfma_f32_16x16x32_bf16(a[mt], bl[nt], acc2[mt][nt], 0, 0, 0);
            }
        __syncthreads();
    }

    const size_t zb = (size_t)blockIdx.z << 20;
#pragma unroll
    for (int mt = 0; mt < 4; ++mt)
#pragma unroll
        for (int nt = 0; nt < 2; ++nt)
#pragma unroll
            for (int r = 0; r < 4; ++r) {
                int cg = c0 + wm + (mt << 4) + (q << 2) + r;   // D row = (L>>4)*4 + reg
                int dg = d0 + wn + (nt << 4) + lm;             // D col = L&15
                size_t o = zb + ((size_t)cg << 10) + dg;
                g1[o] = acc1[mt][nt][r];
                g2[o] = acc2[mt][nt][r];
            }
}

// ---------------- K3: E = sum_z (G1 + G2) + (sum_z G2)^T, 64x64 tiles ----------------
__global__ __launch_bounds__(256) void k_reduce(const float* __restrict__ g1,
                                                const float* __restrict__ g2,
                                                float* __restrict__ E,
                                                int splitk) {
    __shared__ float ld[64][65];
    const int t = threadIdx.x;
    const int i = t >> 2;              // row 0..63
    const int jb = (t & 3) << 4;       // col chunk base 0/16/32/48
    const int c0 = blockIdx.y << 6;
    const int d0 = blockIdx.x << 6;

    float acc[16];
#pragma unroll
    for (int u = 0; u < 16; ++u) acc[u] = 0.0f;

    for (int z = 0; z < splitk; ++z) {
        const size_t zb = (size_t)z << 20;
        const float* p1 = g1 + zb + ((size_t)(c0 + i) << 10) + d0 + jb;
        const float* p2 = g2 + zb + ((size_t)(c0 + i) << 10) + d0 + jb;
        const float* pt = g2 + zb + ((size_t)(d0 + i) << 10) + c0 + jb;
#pragma unroll
        for (int u4 = 0; u4 < 4; ++u4) {
            float4 v1 = ((const float4*)p1)[u4];
            float4 v2 = ((const float4*)p2)[u4];
            acc[u4 * 4 + 0] += v1.x + v2.x;
            acc[u4 * 4 + 1] += v1.y + v2.y;
            acc[u4 * 4 + 2] += v1.z + v2.z;
            acc[u4 * 4 + 3] += v1.w + v2.w;
        }
        __syncthreads();   // previous iter's LDS reads done
#pragma unroll
        for (int u4 = 0; u4 < 4; ++u4)
            *(float4*)&ld[i][jb + u4 * 4] = ((const float4*)pt)[u4];
        __syncthreads();
#pragma unroll
        for (int u = 0; u < 16; ++u)
            acc[u] += ld[jb + u][i];   // g2[d0+jb+u][c0+i]
    }

    float* eo = E + ((size_t)(c0 + i) << 10) + d0 + jb;
#pragma unroll
    for (int u4 = 0; u4 < 4; ++u4) {
        float4 v;
        v.x = acc[u4 * 4 + 0]; v.y = acc[u4 * 4 + 1];
        v.z = acc[u4 * 4 + 2]; v.w = acc[u4 * 4 + 3];
        ((float4*)eo)[u4] = v;
    }
}

// ---------------- K4: row softmax: A = softmax(rowmin(E) - E) ----------------
__global__ __launch_bounds__(256) void k_softmax(const float* __restrict__ E,
                                                 ushort_t* __restrict__ att) {
    const int c = blockIdx.x;
    const int t = threadIdx.x;
    __shared__ float red[4];
    __shared__ float bcast;

    float4 e4 = ((const float4*)E)[((size_t)c << 8) + t];
    float m = fminf(fminf(e4.x, e4.y), fminf(e4.z, e4.w));
#pragma unroll
    for (int off = 32; off > 0; off >>= 1) m = fminf(m, __shfl_down(m, off));
    if ((t & 63) == 0) red[t >> 6] = m;
    __syncthreads();
    if (t == 0) bcast = fminf(fminf(red[0], red[1]), fminf(red[2], red[3]));
    __syncthreads();
    m = bcast;

    float w0 = expf(m - e4.x), w1 = expf(m - e4.y);
    float w2 = expf(m - e4.z), w3 = expf(m - e4.w);
    float s = w0 + w1 + w2 + w3;
#pragma unroll
    for (int off = 32; off > 0; off >>= 1) s += __shfl_down(s, off);
    if ((t & 63) == 0) red[t >> 6] = s;
    __syncthreads();
    if (t == 0) bcast = red[0] + red[1] + red[2] + red[3];
    __syncthreads();
    float inv = 1.0f / bcast;
    ushort4 o;
    o.x = f2b(w0 * inv); o.y = f2b(w1 * inv);
    o.z = f2b(w2 * inv); o.w = f2b(w3 * inv);
    ((ushort4*)att)[((size_t)c << 8) + t] = o;
}

// ---------------- K5: transpose Ph [1024][36864] -> PhT [36864][1024] ----------------
__global__ __launch_bounds__(256) void k_transpose(const ushort_t* __restrict__ ph,
                                                   ushort_t* __restrict__ pht) {
    __shared__ __align__(16) ushort_t tile[64][72];   // pad 8 to keep 16B alignment
    const int t = threadIdx.x;
    const int i = t >> 2, qd = t & 3;
    const int c0 = blockIdx.y << 6;
    const size_t n0 = (size_t)blockIdx.x << 6;

    const ushort_t* src = ph + (size_t)(c0 + i) * N_DIM + n0 + (qd << 4);
    uint4 v0 = *(const uint4*)src;
    uint4 v1 = *(const uint4*)(src + 8);
    *(uint4*)&tile[i][qd << 4]       = v0;
    *(uint4*)&tile[i][(qd << 4) + 8] = v1;
    __syncthreads();

    ushort_t tmp[16];
#pragma unroll
    for (int u = 0; u < 16; ++u) tmp[u] = tile[(qd << 4) + u][i];
    ushort_t* dst = pht + (n0 + i) * C_DIM + c0 + (qd << 4);
    *(uint4*)dst       = *(uint4*)tmp;
    *(uint4*)(dst + 8) = *(uint4*)(tmp + 8);
}

// ---------------- K6: O = A * P, out = gamma*O + x. 128x128 tile, 4 waves of 64x64 ----------------
__global__ __launch_bounds__(256) void k_ogemm(const ushort_t* __restrict__ att,
                                               const ushort_t* __restrict__ pht,
                                               const float* __restrict__ x,
                                               const float* __restrict__ gamma,
                                               float* __restrict__ out) {
    __shared__ __align__(16) ushort_t sA[128 * 32];
    __shared__ __align__(16) ushort_t sB[128 * 32];

    const int t = threadIdx.x;
    const int w = t >> 6, L = t & 63;
    const int n0 = blockIdx.x << 7;
    const int c0 = blockIdx.y << 7;
    const int srow = L >> 2, scol = (L & 3) << 3;

    const int wm = (w >> 1) << 6, wn = (w & 1) << 6;
    const int lm = L & 15, q = L >> 4;

    f32x4 acc[4][4];
#pragma unroll
    for (int a = 0; a < 4; ++a)
#pragma unroll
        for (int b = 0; b < 4; ++b) acc[a][b] = (f32x4)0.0f;

    for (int k = 0; k < C_DIM; k += 32) {
#pragma unroll
        for (int j = 0; j < 4; ++j) {
            int ch = (w << 2) + j;                    // 0..7 -> sA rows, 8..15 -> sB rows
            int row = ((ch & 7) << 4) + srow;
            const ushort_t* src = (ch < 8)
                ? att + (size_t)(c0 + row) * C_DIM + k + scol
                : pht + (size_t)(n0 + row) * C_DIM + k + scol;
            ushort_t* base = (ch < 8) ? sA : sB;
            async16(src, base + (((ch & 7) << 4) << 5));
        }
        __syncthreads();

        bf16x8 a[4], b[4];
#pragma unroll
        for (int mt = 0; mt < 4; ++mt)
            a[mt] = *(const bf16x8*)(sA + ((wm + (mt << 4) + lm) << 5) + (q << 3));
#pragma unroll
        for (int nt = 0; nt < 4; ++nt)
            b[nt] = *(const bf16x8*)(sB + ((wn + (nt << 4) + lm) << 5) + (q << 3));
#pragma unroll
        for (int mt = 0; mt < 4; ++mt)
#pragma unroll
            for (int nt = 0; nt < 4; ++nt)
                acc[mt][nt] = __builtin_amdgcn_mfma_f32_16x16x32_bf16(a[mt], b[nt], acc[mt][nt], 0, 0, 0);
        __syncthreads();
    }

    const float g = gamma[0];
#pragma unroll
    for (int mt = 0; mt < 4; ++mt)
#pragma unroll
        for (int nt = 0; nt < 4; ++nt)
#pragma unroll
            for (int r = 0; r < 4; ++r) {
                int cg = c0 + wm + (mt << 4) + (q << 2) + r;
                int ng = n0 + wn + (nt << 4) + lm;
                size_t o = (size_t)cg * N_DIM + ng;
                out[o] = g * acc[mt][nt][r] + x[o];
            }
}

extern "C" void kernel_launch(void* const* d_in, const int* in_sizes, int n_in,
                              void* d_out, int out_size, void* d_ws, size_t ws_size,
                              hipStream_t stream) {
    const float* x     = (const float*)d_in[0];
    const float* gamma = (const float*)d_in[1];
    float* out = (float*)d_out;
    char* ws = (char*)d_ws;

    // pick split-K by available workspace (g1+g2 need S*8 MiB)
    const size_t PH = 75497472ull, SLICE = 4194304ull, EB = 4194304ull, AT = 2097152ull;
    int S = 8;
    if (ws_size < 2 * PH + (size_t)S * 2 * SLICE + EB + AT) S = 4;
    if (ws_size < 2 * PH + (size_t)S * 2 * SLICE + EB + AT) S = 3;
    const int kchunk = N_DIM / S;

    ushort_t* ph  = (ushort_t*)(ws);
    ushort_t* pl  = (ushort_t*)(ws + PH);
    float*    g1  = (float*)   (ws + 2 * PH);
    float*    g2  = (float*)   (ws + 2 * PH + (size_t)S * SLICE);
    float*    E   = (float*)   (ws + 2 * PH + (size_t)S * 2 * SLICE);
    ushort_t* att = (ushort_t*)(ws + 2 * PH + (size_t)S * 2 * SLICE + EB);
    ushort_t* pht = pl;   // transpose written after E-GEMM has consumed Pl

    k_convert<<<dim3((C_DIM * (size_t)N_DIM / 4) / 256), 256, 0, stream>>>(x, ph, pl);

    k_egemm<<<dim3(8, 16, S), 256, 0, stream>>>(ph, pl, g1, g2, kchunk);

    k_reduce<<<dim3(16, 16), 256, 0, stream>>>(g1, g2, E, S);

    k_softmax<<<dim3(C_DIM), 256, 0, stream>>>(E, att);

    k_transpose<<<dim3(N_DIM / 64, C_DIM / 64), 256, 0, stream>>>(ph, pht);

    k_ogemm<<<dim3(N_DIM / 128, C_DIM / 128), 256, 0, stream>>>(att, pht, x, gamma, out);
}

// Round 3
// 681.012 us; speedup vs baseline: 1.0921x; 1.0240x over previous
//
#include <hip/hip_runtime.h>
#include <cstdint>

#define C_DIM 1024
#define N_DIM 36864   // 192*192

typedef unsigned short ushort_t;
typedef __attribute__((ext_vector_type(8))) short bf16x8;   // 8 bf16 in 4 VGPRs
typedef __attribute__((ext_vector_type(4))) float f32x4;

__device__ __forceinline__ ushort_t f2b(float f) {
    unsigned u = __float_as_uint(f);
    u = (u + 0x7fffu + ((u >> 16) & 1u)) >> 16;   // RN-even
    return (ushort_t)u;
}
__device__ __forceinline__ float b2f(ushort_t b) {
    return __uint_as_float(((unsigned)b) << 16);
}

// async global->LDS, 16B per lane; lds base must be wave-uniform, HW adds lane*16
__device__ __forceinline__ void async16(const void* g, const void* lds) {
    __builtin_amdgcn_global_load_lds(
        (const __attribute__((address_space(1))) unsigned int*)(uintptr_t)g,
        (__attribute__((address_space(3))) unsigned int*)(uint32_t)(uintptr_t)lds,
        16, 0, 0);
}

// ---------------- K1a (fallback): x -> Ph, Pl ----------------
__global__ __launch_bounds__(256) void k_convert(const float* __restrict__ x,
                                                 ushort_t* __restrict__ ph,
                                                 ushort_t* __restrict__ pl) {
    int i = blockIdx.x * 256 + threadIdx.x;        // float4 index
    float4 v = ((const float4*)x)[i];
    ushort4 h, l;
    h.x = f2b(v.x); l.x = f2b(v.x - b2f(h.x));
    h.y = f2b(v.y); l.y = f2b(v.y - b2f(h.y));
    h.z = f2b(v.z); l.z = f2b(v.z - b2f(h.z));
    h.w = f2b(v.w); l.w = f2b(v.w - b2f(h.w));
    ((ushort4*)ph)[i] = h;
    ((ushort4*)pl)[i] = l;
}

// ---------------- K1b (preferred): x -> Ph, Pl, PhT in one pass ----------------
__global__ __launch_bounds__(256) void k_convtrans(const float* __restrict__ x,
                                                   ushort_t* __restrict__ ph,
                                                   ushort_t* __restrict__ pl,
                                                   ushort_t* __restrict__ pht) {
    __shared__ __align__(16) ushort_t th[64][72];
    const int t = threadIdx.x;
    const int i = t >> 2, qd = t & 3;
    const int c0 = blockIdx.y << 6;
    const size_t n0 = (size_t)blockIdx.x << 6;

    const size_t row = (size_t)(c0 + i) * N_DIM + n0 + (qd << 4);
    const float* src = x + row;
    union { ushort_t s[16]; uint4 q[2]; } H, Lo;
#pragma unroll
    for (int u4 = 0; u4 < 4; ++u4) {
        float4 v = ((const float4*)src)[u4];
        ushort_t h0 = f2b(v.x), h1 = f2b(v.y), h2 = f2b(v.z), h3 = f2b(v.w);
        H.s[u4 * 4 + 0] = h0; Lo.s[u4 * 4 + 0] = f2b(v.x - b2f(h0));
        H.s[u4 * 4 + 1] = h1; Lo.s[u4 * 4 + 1] = f2b(v.y - b2f(h1));
        H.s[u4 * 4 + 2] = h2; Lo.s[u4 * 4 + 2] = f2b(v.z - b2f(h2));
        H.s[u4 * 4 + 3] = h3; Lo.s[u4 * 4 + 3] = f2b(v.w - b2f(h3));
    }
    *(uint4*)(ph + row)     = H.q[0];
    *(uint4*)(ph + row + 8) = H.q[1];
    *(uint4*)(pl + row)     = Lo.q[0];
    *(uint4*)(pl + row + 8) = Lo.q[1];
    *(uint4*)&th[i][qd << 4]       = H.q[0];
    *(uint4*)&th[i][(qd << 4) + 8] = H.q[1];
    __syncthreads();

    ushort_t tmp[16];
#pragma unroll
    for (int u = 0; u < 16; ++u) tmp[u] = th[(qd << 4) + u][i];
    ushort_t* dst = pht + (n0 + i) * C_DIM + c0 + (qd << 4);
    *(uint4*)dst       = *(uint4*)tmp;
    *(uint4*)(dst + 8) = *(uint4*)(tmp + 8);
}

// ---------------- K2: E-GEMM partials. G1 = Ph*Ph^T, G2 = Ph*Pl^T ----------------
// tile 128(c) x 64(d), BK=32, 4 waves of 64x32, dual MFMA chain, split-K over gridDim.z
// double-buffered LDS, raw s_barrier + partial vmcnt (prefetch never drained)
__global__ __launch_bounds__(256) void k_egemm(const ushort_t* __restrict__ ph,
                                               const ushort_t* __restrict__ pl,
                                               float* __restrict__ g1,
                                               float* __restrict__ g2,
                                               int kchunk) {
    __shared__ __align__(16) ushort_t sA [2][128 * 32];   // 16 KB
    __shared__ __align__(16) ushort_t sBh[2][64 * 32];    //  8 KB
    __shared__ __align__(16) ushort_t sBl[2][64 * 32];    //  8 KB

    const int t = threadIdx.x;
    const int w = t >> 6;
    const int L = t & 63;
    const int c0 = blockIdx.x << 7;
    const int d0 = blockIdx.y << 6;
    const int kb = blockIdx.z * kchunk;
    const int lrow = L >> 2, lcol = (L & 3) << 3;

    // wave w stages sA rows [32w,32w+32); waves 0,1 stage sBh rows [32(w&1),+32); waves 2,3 sBl
    const ushort_t* gA0 = ph + (size_t)(c0 + (w << 5) + lrow) * N_DIM + kb + lcol;
    const ushort_t* gB0 = (w < 2 ? ph : pl) +
                          (size_t)(d0 + ((w & 1) << 5) + lrow) * N_DIM + kb + lcol;
    ushort_t* lA[2] = { sA[0] + ((w << 5) << 5), sA[1] + ((w << 5) << 5) };
    ushort_t* lB[2] = { (w < 2 ? sBh[0] : sBl[0]) + (((w & 1) << 5) << 5),
                        (w < 2 ? sBh[1] : sBl[1]) + (((w & 1) << 5) << 5) };

    const int wm = (w >> 1) << 6;   // wave row offset (c) 0/64
    const int wn = (w & 1) << 5;    // wave col offset (d) 0/32
    const int lm = L & 15, q = L >> 4;

    f32x4 acc1[4][2], acc2[4][2];
#pragma unroll
    for (int a = 0; a < 4; ++a)
#pragma unroll
        for (int b = 0; b < 2; ++b) { acc1[a][b] = (f32x4)0.0f; acc2[a][b] = (f32x4)0.0f; }

    auto stage = [&](int ti, int b) {
        const ushort_t* ga = gA0 + (ti << 5);
        const ushort_t* gb = gB0 + (ti << 5);
        async16(ga,              lA[b]);
        async16(ga + 16 * N_DIM, lA[b] + 16 * 32);
        async16(gb,              lB[b]);
        async16(gb + 16 * N_DIM, lB[b] + 16 * 32);
    };

    const int nIter = kchunk >> 5;
    stage(0, 0);

    for (int ti = 0; ti < nIter; ++ti) {
        const int cb = ti & 1;
        if (ti + 1 < nIter) {
            stage(ti + 1, cb ^ 1);
            __builtin_amdgcn_s_waitcnt(0x0F74);   // vmcnt(4): tile ti landed; prefetch stays in flight
        } else {
            __builtin_amdgcn_s_waitcnt(0x0F70);   // vmcnt(0): last tile landed
        }
        __builtin_amdgcn_s_barrier();

        bf16x8 a[4], bh[2], bl[2];
#pragma unroll
        for (int mt = 0; mt < 4; ++mt)
            a[mt] = *(const bf16x8*)(sA[cb] + ((wm + (mt << 4) + lm) << 5) + (q << 3));
#pragma unroll
        for (int nt = 0; nt < 2; ++nt) {
            bh[nt] = *(const bf16x8*)(sBh[cb] + ((wn + (nt << 4) + lm) << 5) + (q << 3));
            bl[nt] = *(const bf16x8*)(sBl[cb] + ((wn + (nt << 4) + lm) << 5) + (q << 3));
        }
#pragma unroll
        for (int mt = 0; mt < 4; ++mt)
#pragma unroll
            for (int nt = 0; nt < 2; ++nt) {
                acc1[mt][nt] = __builtin_amdgcn_mfma_f32_16x16x32_bf16(a[mt], bh[nt], acc1[mt][nt], 0, 0, 0);
                acc2[mt][nt] = __builtin_amdgcn_mfma_f32_16x16x32_bf16(a[mt], bl[nt], acc2[mt][nt], 0, 0, 0);
            }
        // all 8 ds_reads consumed by MFMA above (lgkm waits inserted by compiler),
        // so after this barrier it is safe for the next iter to overwrite buffer cb^1
        __builtin_amdgcn_s_barrier();
    }

    const size_t zb = (size_t)blockIdx.z << 20;
#pragma unroll
    for (int mt = 0; mt < 4; ++mt)
#pragma unroll
        for (int nt = 0; nt < 2; ++nt)
#pragma unroll
            for (int r = 0; r < 4; ++r) {
                int cg = c0 + wm + (mt << 4) + (q << 2) + r;   // D row = (L>>4)*4 + reg
                int dg = d0 + wn + (nt << 4) + lm;             // D col = L&15
                size_t o = zb + ((size_t)cg << 10) + dg;
                g1[o] = acc1[mt][nt][r];
                g2[o] = acc2[mt][nt][r];
            }
}

// ---------------- K3: E = sum_z (G1 + G2) + (sum_z G2)^T, 64x64 tiles ----------------
__global__ __launch_bounds__(256) void k_reduce(const float* __restrict__ g1,
                                                const float* __restrict__ g2,
                                                float* __restrict__ E,
                                                int splitk) {
    __shared__ float ld[64][65];
    const int t = threadIdx.x;
    const int i = t >> 2;              // row 0..63
    const int jb = (t & 3) << 4;       // col chunk base 0/16/32/48
    const int c0 = blockIdx.y << 6;
    const int d0 = blockIdx.x << 6;

    float acc[16];
#pragma unroll
    for (int u = 0; u < 16; ++u) acc[u] = 0.0f;

    for (int z = 0; z < splitk; ++z) {
        const size_t zb = (size_t)z << 20;
        const float* p1 = g1 + zb + ((size_t)(c0 + i) << 10) + d0 + jb;
        const float* p2 = g2 + zb + ((size_t)(c0 + i) << 10) + d0 + jb;
        const float* pt = g2 + zb + ((size_t)(d0 + i) << 10) + c0 + jb;
#pragma unroll
        for (int u4 = 0; u4 < 4; ++u4) {
            float4 v1 = ((const float4*)p1)[u4];
            float4 v2 = ((const float4*)p2)[u4];
            acc[u4 * 4 + 0] += v1.x + v2.x;
            acc[u4 * 4 + 1] += v1.y + v2.y;
            acc[u4 * 4 + 2] += v1.z + v2.z;
            acc[u4 * 4 + 3] += v1.w + v2.w;
        }
        __syncthreads();   // previous iter's LDS reads done
#pragma unroll
        for (int u4 = 0; u4 < 4; ++u4)
            *(float4*)&ld[i][jb + u4 * 4] = ((const float4*)pt)[u4];
        __syncthreads();
#pragma unroll
        for (int u = 0; u < 16; ++u)
            acc[u] += ld[jb + u][i];   // g2[d0+jb+u][c0+i]
    }

    float* eo = E + ((size_t)(c0 + i) << 10) + d0 + jb;
#pragma unroll
    for (int u4 = 0; u4 < 4; ++u4) {
        float4 v;
        v.x = acc[u4 * 4 + 0]; v.y = acc[u4 * 4 + 1];
        v.z = acc[u4 * 4 + 2]; v.w = acc[u4 * 4 + 3];
        ((float4*)eo)[u4] = v;
    }
}

// ---------------- K4: row softmax: A = softmax(rowmin(E) - E) ----------------
__global__ __launch_bounds__(256) void k_softmax(const float* __restrict__ E,
                                                 ushort_t* __restrict__ att) {
    const int c = blockIdx.x;
    const int t = threadIdx.x;
    __shared__ float red[4];
    __shared__ float bcast;

    float4 e4 = ((const float4*)E)[((size_t)c << 8) + t];
    float m = fminf(fminf(e4.x, e4.y), fminf(e4.z, e4.w));
#pragma unroll
    for (int off = 32; off > 0; off >>= 1) m = fminf(m, __shfl_down(m, off));
    if ((t & 63) == 0) red[t >> 6] = m;
    __syncthreads();
    if (t == 0) bcast = fminf(fminf(red[0], red[1]), fminf(red[2], red[3]));
    __syncthreads();
    m = bcast;

    float w0 = expf(m - e4.x), w1 = expf(m - e4.y);
    float w2 = expf(m - e4.z), w3 = expf(m - e4.w);
    float s = w0 + w1 + w2 + w3;
#pragma unroll
    for (int off = 32; off > 0; off >>= 1) s += __shfl_down(s, off);
    if ((t & 63) == 0) red[t >> 6] = s;
    __syncthreads();
    if (t == 0) bcast = red[0] + red[1] + red[2] + red[3];
    __syncthreads();
    float inv = 1.0f / bcast;
    ushort4 o;
    o.x = f2b(w0 * inv); o.y = f2b(w1 * inv);
    o.z = f2b(w2 * inv); o.w = f2b(w3 * inv);
    ((ushort4*)att)[((size_t)c << 8) + t] = o;
}

// ---------------- K5 (fallback): transpose Ph -> PhT ----------------
__global__ __launch_bounds__(256) void k_transpose(const ushort_t* __restrict__ ph,
                                                   ushort_t* __restrict__ pht) {
    __shared__ __align__(16) ushort_t tile[64][72];
    const int t = threadIdx.x;
    const int i = t >> 2, qd = t & 3;
    const int c0 = blockIdx.y << 6;
    const size_t n0 = (size_t)blockIdx.x << 6;

    const ushort_t* src = ph + (size_t)(c0 + i) * N_DIM + n0 + (qd << 4);
    uint4 v0 = *(const uint4*)src;
    uint4 v1 = *(const uint4*)(src + 8);
    *(uint4*)&tile[i][qd << 4]       = v0;
    *(uint4*)&tile[i][(qd << 4) + 8] = v1;
    __syncthreads();

    ushort_t tmp[16];
#pragma unroll
    for (int u = 0; u < 16; ++u) tmp[u] = tile[(qd << 4) + u][i];
    ushort_t* dst = pht + (n0 + i) * C_DIM + c0 + (qd << 4);
    *(uint4*)dst       = *(uint4*)tmp;
    *(uint4*)(dst + 8) = *(uint4*)(tmp + 8);
}

// ---------------- K6: O = A * P, out = gamma*O + x. 128x128 tile, 4 waves of 64x64 ----------------
__global__ __launch_bounds__(256) void k_ogemm(const ushort_t* __restrict__ att,
                                               const ushort_t* __restrict__ pht,
                                               const float* __restrict__ x,
                                               const float* __restrict__ gamma,
                                               float* __restrict__ out) {
    __shared__ __align__(16) ushort_t sA[128 * 32];
    __shared__ __align__(16) ushort_t sB[128 * 32];

    const int t = threadIdx.x;
    const int w = t >> 6, L = t & 63;
    const int n0 = blockIdx.x << 7;
    const int c0 = blockIdx.y << 7;
    const int srow = L >> 2, scol = (L & 3) << 3;

    const int wm = (w >> 1) << 6, wn = (w & 1) << 6;
    const int lm = L & 15, q = L >> 4;

    f32x4 acc[4][4];
#pragma unroll
    for (int a = 0; a < 4; ++a)
#pragma unroll
        for (int b = 0; b < 4; ++b) acc[a][b] = (f32x4)0.0f;

    for (int k = 0; k < C_DIM; k += 32) {
#pragma unroll
        for (int j = 0; j < 4; ++j) {
            int ch = (w << 2) + j;                    // 0..7 -> sA rows, 8..15 -> sB rows
            int row = ((ch & 7) << 4) + srow;
            const ushort_t* src = (ch < 8)
                ? att + (size_t)(c0 + row) * C_DIM + k + scol
                : pht + (size_t)(n0 + row) * C_DIM + k + scol;
            ushort_t* base = (ch < 8) ? sA : sB;
            async16(src, base + (((ch & 7) << 4) << 5));
        }
        __syncthreads();

        bf16x8 a[4], b[4];
#pragma unroll
        for (int mt = 0; mt < 4; ++mt)
            a[mt] = *(const bf16x8*)(sA + ((wm + (mt << 4) + lm) << 5) + (q << 3));
#pragma unroll
        for (int nt = 0; nt < 4; ++nt)
            b[nt] = *(const bf16x8*)(sB + ((wn + (nt << 4) + lm) << 5) + (q << 3));
#pragma unroll
        for (int mt = 0; mt < 4; ++mt)
#pragma unroll
            for (int nt = 0; nt < 4; ++nt)
                acc[mt][nt] = __builtin_amdgcn_mfma_f32_16x16x32_bf16(a[mt], b[nt], acc[mt][nt], 0, 0, 0);
        __syncthreads();
    }

    const float g = gamma[0];
#pragma unroll
    for (int mt = 0; mt < 4; ++mt)
#pragma unroll
        for (int nt = 0; nt < 4; ++nt)
#pragma unroll
            for (int r = 0; r < 4; ++r) {
                int cg = c0 + wm + (mt << 4) + (q << 2) + r;
                int ng = n0 + wn + (nt << 4) + lm;
                size_t o = (size_t)cg * N_DIM + ng;
                out[o] = g * acc[mt][nt][r] + x[o];
            }
}

extern "C" void kernel_launch(void* const* d_in, const int* in_sizes, int n_in,
                              void* d_out, int out_size, void* d_ws, size_t ws_size,
                              hipStream_t stream) {
    const float* x     = (const float*)d_in[0];
    const float* gamma = (const float*)d_in[1];
    float* out = (float*)d_out;
    char* ws = (char*)d_ws;

    const size_t P = 75497472ull, SL = 4194304ull, EB = 4194304ull, AT = 2097152ull;

    // preferred: fused convert+transpose (needs 3 P-arrays) with S=8
    int S = 8;
    bool fused = (ws_size >= 3 * P + (size_t)S * 2 * SL + EB + AT);
    if (!fused) {
        if (ws_size < 2 * P + (size_t)S * 2 * SL + EB + AT) S = 4;
        if (ws_size < 2 * P + (size_t)S * 2 * SL + EB + AT) S = 3;
    }
    const int kchunk = N_DIM / S;

    if (fused) {
        ushort_t* ph  = (ushort_t*)(ws);
        ushort_t* pl  = (ushort_t*)(ws + P);
        ushort_t* pht = (ushort_t*)(ws + 2 * P);
        float*    g1  = (float*)   (ws + 3 * P);
        float*    g2  = (float*)   (ws + 3 * P + (size_t)S * SL);
        float*    E   = (float*)   (ws + 3 * P + (size_t)S * 2 * SL);
        ushort_t* att = (ushort_t*)(ws + 3 * P + (size_t)S * 2 * SL + EB);

        k_convtrans<<<dim3(N_DIM / 64, C_DIM / 64), 256, 0, stream>>>(x, ph, pl, pht);
        k_egemm<<<dim3(8, 16, S), 256, 0, stream>>>(ph, pl, g1, g2, kchunk);
        k_reduce<<<dim3(16, 16), 256, 0, stream>>>(g1, g2, E, S);
        k_softmax<<<dim3(C_DIM), 256, 0, stream>>>(E, att);
        k_ogemm<<<dim3(N_DIM / 128, C_DIM / 128), 256, 0, stream>>>(att, pht, x, gamma, out);
    } else {
        ushort_t* ph  = (ushort_t*)(ws);
        ushort_t* pl  = (ushort_t*)(ws + P);
        float*    g1  = (float*)   (ws + 2 * P);
        float*    g2  = (float*)   (ws + 2 * P + (size_t)S * SL);
        float*    E   = (float*)   (ws + 2 * P + (size_t)S * 2 * SL);
        ushort_t* att = (ushort_t*)(ws + 2 * P + (size_t)S * 2 * SL + EB);
        ushort_t* pht = pl;   // transpose written after E-GEMM has consumed Pl

        k_convert<<<dim3((C_DIM * (size_t)N_DIM / 4) / 256), 256, 0, stream>>>(x, ph, pl);
        k_egemm<<<dim3(8, 16, S), 256, 0, stream>>>(ph, pl, g1, g2, kchunk);
        k_reduce<<<dim3(16, 16), 256, 0, stream>>>(g1, g2, E, S);
        k_softmax<<<dim3(C_DIM), 256, 0, stream>>>(E, att);
        k_transpose<<<dim3(N_DIM / 64, C_DIM / 64), 256, 0, stream>>>(ph, pht);
        k_ogemm<<<dim3(N_DIM / 128, C_DIM / 128), 256, 0, stream>>>(att, pht, x, gamma, out);
    }
}